// Round 25
// baseline (1092.768 us; speedup 1.0000x reference)
//
#include <hip/hip_runtime.h>
#include <cstdint>

#define B_ROWS 65536
#define D_IN   640
#define D_LAT  2560
#define K_SEL  32
#define NCAND  48
#define CCAP   64      // candidate capacity per row
#define DELTA  0.04f   // ambiguity half-window: covers bf16 ulp (0.0156) + GEMM err
// np-exact K-panel boundaries (OpenBLAS SKYLAKEX Q=192): 192+192+128+128
#define P1 192
#define P2 384
#define P3 512
// merged prep kernel block ranges
#define PREP_X  ((size_t)B_ROWS * D_IN / 1024)            // 40960
#define PREP_W  ((size_t)D_LAT * D_IN / 1024)             // 1600
#define PREP_T  ((D_LAT / 32) * (D_IN / 32))              // 1600

typedef __attribute__((ext_vector_type(8))) short short8;
typedef __attribute__((ext_vector_type(4))) float f32x4;

static __device__ __forceinline__ ushort f2bf(float f) {
    uint32_t u = __float_as_uint(f);
    u += 0x7fffu + ((u >> 16) & 1u);   // round-to-nearest-even
    return (ushort)(u >> 16);
}
static __device__ __forceinline__ float b2f(ushort u) {
    return __uint_as_float((uint32_t)u << 16);
}

// ---------------- merged prep: cvt x -> xB, cvt W_enc -> WeB, W_dec^T -> WdTb ----
__global__ __launch_bounds__(256) void prep_kernel(const float* __restrict__ x,
                                                   const float* __restrict__ We,
                                                   const float* __restrict__ Wd,
                                                   ushort* __restrict__ xB,
                                                   ushort* __restrict__ WeB,
                                                   ushort* __restrict__ WdTb) {
    __shared__ float t[32][33];
    const size_t b = blockIdx.x;
    if (b < PREP_X + PREP_W) {
        const float* src = (b < PREP_X) ? x : We;
        ushort* dst      = (b < PREP_X) ? xB : WeB;
        const size_t bb  = (b < PREP_X) ? b : (b - PREP_X);
        const size_t i = (bb * 256 + threadIdx.x) * 4;
        float4 v = *(const float4*)(src + i);
        ushort4 o;
        o.x = f2bf(v.x); o.y = f2bf(v.y); o.z = f2bf(v.z); o.w = f2bf(v.w);
        *(ushort4*)(dst + i) = o;
    } else {
        const int tb = (int)(b - PREP_X - PREP_W);
        const int j0 = (tb % (D_LAT / 32)) * 32;
        const int i0 = (tb / (D_LAT / 32)) * 32;
        const int tx = threadIdx.x & 31, ty = threadIdx.x >> 5;
#pragma unroll
        for (int q = 0; q < 4; ++q)
            t[ty + 8 * q][tx] = Wd[(size_t)(i0 + ty + 8 * q) * D_LAT + j0 + tx];
        __syncthreads();
#pragma unroll
        for (int q = 0; q < 4; ++q)
            WdTb[(size_t)(j0 + ty + 8 * q) * D_IN + i0 + tx] = f2bf(t[tx][ty + 8 * q]);
    }
}

// ---------------- bf16 MFMA filter GEMM -> bf16 latents (BK=64) ------------------
// K-step 64: half the barriers, 32 MFMA/phase. Per-acc MFMA order identical to
// BK=32 (ks ascending within kt == former kt,kt+1) -> bit-identical latents.
__global__ __launch_bounds__(256, 3) void enc_mfma(const ushort* __restrict__ A,
                                                   const ushort* __restrict__ Wb,
                                                   const float* __restrict__ bias,
                                                   ushort* __restrict__ C) {
    __shared__ ushort Al[128][72];   // pad 64->72 (144B row): banks (fr*4)%32, 2-way
    __shared__ ushort Bl[128][72];
    const int tid = threadIdx.x;
    const int n0 = blockIdx.x * 128;
    const int m0 = blockIdx.y * 128;
    const int srow = tid >> 1, shalf = tid & 1;   // 2 threads/row, 64B each
    const ushort* Ap = A  + (size_t)(m0 + srow) * D_IN + shalf * 32;
    const ushort* Bp = Wb + (size_t)(n0 + srow) * D_IN + shalf * 32;

    const int w = tid >> 6, l = tid & 63;
    const int wm = w >> 1, wn = w & 1;
    const int fr = l & 15, ko = l >> 4;

    f32x4 acc[4][4];
#pragma unroll
    for (int i = 0; i < 4; ++i)
#pragma unroll
        for (int j = 0; j < 4; ++j) acc[i][j] = (f32x4)0.0f;

    uint4 a0, a1, a2, a3, b0, b1, b2, b3;
#define LOADT(KT)                                                    \
    {                                                                \
        const uint* ap = (const uint*)(Ap + (KT) * 64);              \
        a0 = *(const uint4*)(ap);                                    \
        a1 = *(const uint4*)(ap + 4);                                \
        a2 = *(const uint4*)(ap + 8);                                \
        a3 = *(const uint4*)(ap + 12);                               \
        const uint* bp = (const uint*)(Bp + (KT) * 64);              \
        b0 = *(const uint4*)(bp);                                    \
        b1 = *(const uint4*)(bp + 4);                                \
        b2 = *(const uint4*)(bp + 8);                                \
        b3 = *(const uint4*)(bp + 12);                               \
    }

    LOADT(0);
    const int NT = D_IN / 64;   // 10
    for (int kt = 0; kt < NT; ++kt) {
        *(uint4*)&Al[srow][shalf * 32]      = a0;
        *(uint4*)&Al[srow][shalf * 32 + 8]  = a1;
        *(uint4*)&Al[srow][shalf * 32 + 16] = a2;
        *(uint4*)&Al[srow][shalf * 32 + 24] = a3;
        *(uint4*)&Bl[srow][shalf * 32]      = b0;
        *(uint4*)&Bl[srow][shalf * 32 + 8]  = b1;
        *(uint4*)&Bl[srow][shalf * 32 + 16] = b2;
        *(uint4*)&Bl[srow][shalf * 32 + 24] = b3;
        __syncthreads();
        if (kt + 1 < NT) LOADT(kt + 1);

#pragma unroll
        for (int ks = 0; ks < 2; ++ks) {
            short8 af[4], bf[4];
#pragma unroll
            for (int fm = 0; fm < 4; ++fm)
                af[fm] = *(const short8*)&Al[wm * 64 + fm * 16 + fr][ks * 32 + ko * 8];
#pragma unroll
            for (int fn = 0; fn < 4; ++fn)
                bf[fn] = *(const short8*)&Bl[wn * 64 + fn * 16 + fr][ks * 32 + ko * 8];
#pragma unroll
            for (int fm = 0; fm < 4; ++fm)
#pragma unroll
                for (int fn = 0; fn < 4; ++fn)
                    acc[fm][fn] = __builtin_amdgcn_mfma_f32_16x16x32_bf16(
                        af[fm], bf[fn], acc[fm][fn], 0, 0, 0);
        }
        __syncthreads();
    }
#undef LOADT

#pragma unroll
    for (int fn = 0; fn < 4; ++fn) {
        const int col = n0 + wn * 64 + fn * 16 + fr;
        const float bb = bias[col];
#pragma unroll
        for (int fm = 0; fm < 4; ++fm) {
#pragma unroll
            for (int j = 0; j < 4; ++j) {
                const int row = m0 + wm * 64 + fm * 16 + ko * 4 + j;
                C[(size_t)row * D_LAT + col] = f2bf(acc[fm][fn][j] + bb);
            }
        }
    }
}

// ---------------- Candidate select by threshold (wave-per-row, bf16 latents) -----
__global__ __launch_bounds__(256) void topk_cand(const ushort* __restrict__ lat,
                                                 int* __restrict__ cidx,
                                                 float* __restrict__ cval,
                                                 int* __restrict__ ccnt) {
    const int wv = threadIdx.x >> 6, lane = threadIdx.x & 63;
    const int r = blockIdx.x * 4 + wv;
    const ushort* row = lat + (size_t)r * D_LAT;

    float v[5][8];
#pragma unroll
    for (int e = 0; e < 5; ++e) {
        const uint4 u = *(const uint4*)(row + e * 512 + lane * 8);
        v[e][0] = __uint_as_float(u.x << 16);
        v[e][1] = __uint_as_float(u.x & 0xffff0000u);
        v[e][2] = __uint_as_float(u.y << 16);
        v[e][3] = __uint_as_float(u.y & 0xffff0000u);
        v[e][4] = __uint_as_float(u.z << 16);
        v[e][5] = __uint_as_float(u.z & 0xffff0000u);
        v[e][6] = __uint_as_float(u.w << 16);
        v[e][7] = __uint_as_float(u.w & 0xffff0000u);
    }

    float mx = v[0][0];
#pragma unroll
    for (int e = 0; e < 5; ++e)
#pragma unroll
        for (int t = 0; t < 8; ++t) mx = fmaxf(mx, v[e][t]);
#pragma unroll
    for (int off = 1; off < 64; off <<= 1) mx = fmaxf(mx, __shfl_xor(mx, off));

    auto countGt = [&](float t) -> int {
        int c = 0;
#pragma unroll
        for (int e = 0; e < 5; ++e)
#pragma unroll
            for (int q = 0; q < 8; ++q) c += (v[e][q] > t);
#pragma unroll
        for (int off = 1; off < 64; off <<= 1) c += __shfl_xor(c, off);
        return c;
    };

    float lo = mx - 2.0f;
    int clo = countGt(lo);
    if (clo < NCAND) { lo = mx - 4.0f; clo = countGt(lo); }
    if (clo < NCAND) { lo = mx - 16.0f; clo = countGt(lo); }   // paranoia tier
    float hi = mx;
    for (int it = 0; it < 28 && clo > CCAP; ++it) {
        const float mid = 0.5f * (lo + hi);
        const int c = countGt(mid);
        if (c >= NCAND) { lo = mid; clo = c; } else hi = mid;
    }

    int base = 0;
#pragma unroll
    for (int e = 0; e < 5; ++e) {
#pragma unroll
        for (int q = 0; q < 8; ++q) {
            const float val = v[e][q];
            const bool take = val > lo;
            const uint64_t m = __ballot(take);
            const int pos = base + __popcll(m & ((1ull << lane) - 1ull));
            if (take && pos < CCAP) {
                cidx[(size_t)r * CCAP + pos] = e * 512 + lane * 8 + q;
                cval[(size_t)r * CCAP + pos] = val;
            }
            base += __popcll(m);
        }
    }
    if (lane == 0) ccnt[r] = (base < CCAP) ? base : CCAP;
}

// ---------------- Boundary-window refine + select (wave-per-row) -----------------
__global__ __launch_bounds__(256, 4) void refine_sel(const float* __restrict__ x,
                                                     const float* __restrict__ We,
                                                     const float* __restrict__ be,
                                                     const int* __restrict__ cidx,
                                                     const float* __restrict__ cval,
                                                     const int* __restrict__ ccnt,
                                                     float* __restrict__ vals,
                                                     int* __restrict__ idxs) {
    const int wv = threadIdx.x >> 6, lane = threadIdx.x & 63;
    const int r = blockIdx.x * 4 + wv;

    __shared__ float xs[4][656];     // panel bases 0,196,392,524 (banks 0,4,8,12)
    __shared__ int   winj[4][CCAP];
    __shared__ float exv[4][CCAP];

    const int cnt = ccnt[r];

    if (lane < K_SEL) {
        vals[(size_t)r * K_SEL + lane] = 0.f;
        idxs[(size_t)r * K_SEL + lane] = 0;
    }

    for (int i = lane; i < D_IN; i += 64) {
        const int p  = (i >= P3) ? 3 : (i >= P2) ? 2 : (i >= P1) ? 1 : 0;
        const int kb = (p == 0) ? 0 : (p == 1) ? P1  : (p == 2) ? P2  : P3;
        const int pb = (p == 0) ? 0 : (p == 1) ? 196 : (p == 2) ? 392 : 524;
        xs[wv][pb + i - kb] = x[(size_t)r * D_IN + i];
    }

    float v = -__builtin_inff(); int j = 0x7fffffff;
    if (lane < cnt) {
        j = cidx[(size_t)r * CCAP + lane];
        v = cval[(size_t)r * CCAP + lane];
    }

    float mxv = v, mnv = (lane < cnt) ? v : __builtin_inff();
#pragma unroll
    for (int off = 1; off < 64; off <<= 1) {
        mxv = fmaxf(mxv, __shfl_xor(mxv, off));
        mnv = fminf(mnv, __shfl_xor(mnv, off));
    }
    auto cgt = [&](float t) -> int {
        int c = (v > t) ? 1 : 0;
#pragma unroll
        for (int off = 1; off < 64; off <<= 1) c += __shfl_xor(c, off);
        return c;
    };
    float blo = mnv - 0.01f, bhi = mxv;
    for (int it = 0; it < 20; ++it) {
        const float mid = 0.5f * (blo + bhi);
        if (cgt(mid) >= K_SEL) blo = mid; else bhi = mid;
    }
    const float v32a = blo;
    const bool sure_in = (lane < cnt) && (v > v32a + DELTA);
    const bool inwin   = (lane < cnt) && !sure_in && (v > v32a - DELTA);
    const int n_in = __popcll(__ballot(sure_in));
    const uint64_t wm = __ballot(inwin);
    const int wcnt = __popcll(wm);
    if (inwin) winj[wv][__popcll(wm & ((1ull << lane) - 1ull))] = j;

    __syncthreads();

#define BURST(B)                                                     \
    {                                                                \
        const float4 w0 = wp4[(B) * 4 + 0], w1 = wp4[(B) * 4 + 1];   \
        const float4 w2 = wp4[(B) * 4 + 2], w3 = wp4[(B) * 4 + 3];   \
        const float4 x0 = xp4[(B) * 4 + 0], x1 = xp4[(B) * 4 + 1];   \
        const float4 x2 = xp4[(B) * 4 + 2], x3 = xp4[(B) * 4 + 3];   \
        a = fmaf(w0.x, x0.x, a); a = fmaf(w0.y, x0.y, a);            \
        a = fmaf(w0.z, x0.z, a); a = fmaf(w0.w, x0.w, a);            \
        a = fmaf(w1.x, x1.x, a); a = fmaf(w1.y, x1.y, a);            \
        a = fmaf(w1.z, x1.z, a); a = fmaf(w1.w, x1.w, a);            \
        a = fmaf(w2.x, x2.x, a); a = fmaf(w2.y, x2.y, a);            \
        a = fmaf(w2.z, x2.z, a); a = fmaf(w2.w, x2.w, a);            \
        a = fmaf(w3.x, x3.x, a); a = fmaf(w3.y, x3.y, a);            \
        a = fmaf(w3.z, x3.z, a); a = fmaf(w3.w, x3.w, a);            \
    }

    for (int p0 = 0; p0 < wcnt; p0 += 16) {
        const int rank = p0 + (lane >> 2), pnl = lane & 3;
        float a = 0.f; int jj = 0;
        if (rank < wcnt) {
            jj = winj[wv][rank];
            const int k0 = (pnl == 0) ? 0 : (pnl == 1) ? P1  : (pnl == 2) ? P2  : P3;
            const int pb = (pnl == 0) ? 0 : (pnl == 1) ? 196 : (pnl == 2) ? 392 : 524;
            const float4* wp4 = (const float4*)(We + (size_t)jj * D_IN + k0);
            const float4* xp4 = (const float4*)&xs[wv][pb];
            if (pnl < 2) {
#pragma unroll
                for (int b = 0; b < 12; ++b) BURST(b)
            } else {
#pragma unroll
                for (int b = 0; b < 8; ++b) BURST(b)
            }
        }
        const int gb = lane & ~3;
        const float a0 = __shfl(a, gb + 0), a1 = __shfl(a, gb + 1);
        const float a2 = __shfl(a, gb + 2), a3 = __shfl(a, gb + 3);
        if (pnl == 0 && rank < wcnt)
            exv[wv][rank] = (((a0 + a1) + a2) + a3) + be[jj];
    }
#undef BURST
    __syncthreads();

    const uint64_t sm = __ballot(sure_in);
    if (sure_in) {
        const int pos = __popcll(sm & ((1ull << lane) - 1ull));
        vals[(size_t)r * K_SEL + pos] = v;
        idxs[(size_t)r * K_SEL + pos] = j;
    }

    float ev = (lane < wcnt) ? exv[wv][lane] : -__builtin_inff();
    int   ej = (lane < wcnt) ? winj[wv][lane] : 0x7fffffff;
    int need = K_SEL - n_in;
    if (need > wcnt) need = wcnt;    // defensive
    for (int t = 0; t < need; ++t) {
        float bv = ev; int bi = ej;
#pragma unroll
        for (int off = 1; off < 64; off <<= 1) {
            float ov = __shfl_xor(bv, off);
            int   oi = __shfl_xor(bi, off);
            if (ov > bv || (ov == bv && oi < bi)) { bv = ov; bi = oi; }
        }
        if (ej == bi && ej != 0x7fffffff) {   // unique winner lane
            vals[(size_t)r * K_SEL + n_in + t] = ev;
            idxs[(size_t)r * K_SEL + n_in + t] = ej;
            ev = -__builtin_inff(); ej = 0x7fffffff;
        }
    }
}

// ---------------- Decoder + sparse scatter (zeros provided by memset node) -------
__global__ __launch_bounds__(256) void dec_kernel(const float* __restrict__ vals,
                                                  const int* __restrict__ idxs,
                                                  const ushort* __restrict__ WdTb,
                                                  const float* __restrict__ bdec,
                                                  float* __restrict__ recon,
                                                  float* __restrict__ sparse) {
    const int wave = threadIdx.x >> 6, lane = threadIdx.x & 63;
    const int r = blockIdx.x * 4 + wave;

    float lv = 0.f; int li = 0;
    if (lane < K_SEL) {
        lv = vals[(size_t)r * K_SEL + lane];
        li = idxs[(size_t)r * K_SEL + lane];
        li = (li < 0) ? 0 : ((li >= D_LAT) ? D_LAT - 1 : li);   // defensive clamp
    }
    // scatter early (sparse already zeroed by the preceding memset node)
    if (lane < K_SEL && lv != 0.f) sparse[(size_t)r * D_LAT + li] = lv;

    float acc[10];
    {
        const float2* bd2 = (const float2*)bdec;
#pragma unroll
        for (int t = 0; t < 5; ++t) {
            const float2 b2 = bd2[lane * 5 + t];
            acc[2 * t] = b2.x; acc[2 * t + 1] = b2.y;
        }
    }

#pragma unroll 4
    for (int k = 0; k < K_SEL; ++k) {
        float vkv = __shfl(lv, k);
        int   jj  = __shfl(li, k);
        const uint* wu = (const uint*)(WdTb + (size_t)jj * D_IN);
#pragma unroll
        for (int t = 0; t < 5; ++t) {
            const uint u = wu[lane * 5 + t];
            acc[2 * t]     = fmaf(vkv, __uint_as_float(u << 16), acc[2 * t]);
            acc[2 * t + 1] = fmaf(vkv, __uint_as_float(u & 0xffff0000u), acc[2 * t + 1]);
        }
    }
    float2* out2 = (float2*)(recon + (size_t)r * D_IN);
#pragma unroll
    for (int t = 0; t < 5; ++t) {
        float2 o; o.x = acc[2 * t]; o.y = acc[2 * t + 1];
        out2[lane * 5 + t] = o;
    }
}

extern "C" void kernel_launch(void* const* d_in, const int* in_sizes, int n_in,
                              void* d_out, int out_size, void* d_ws, size_t ws_size,
                              hipStream_t stream) {
    const float* x     = (const float*)d_in[0];
    const float* W_enc = (const float*)d_in[1];
    const float* b_enc = (const float*)d_in[2];
    const float* W_dec = (const float*)d_in[3];
    const float* b_dec = (const float*)d_in[4];

    float* recon  = (float*)d_out;                                  // [B][640]
    float* sparse = (float*)d_out + (size_t)B_ROWS * D_IN;          // [B][2560]

    // xB (bf16 x, 84MB) parks in recon region; latB (bf16 latents, 336MB) parks in
    // the sparse region (both consumed before the memset/dec stage).
    ushort* xB   = (ushort*)recon;
    ushort* latB = (ushort*)sparse;

    char* ws = (char*)d_ws;
    size_t off = 0;
    ushort* WdTb = (ushort*)(ws + off); off += (size_t)D_LAT * D_IN * 2;    // 3.28 MB
    ushort* WeB  = (ushort*)(ws + off); off += (size_t)D_LAT * D_IN * 2;    // 3.28 MB
    int*    cidx = (int*)   (ws + off); off += (size_t)B_ROWS * CCAP * 4;   // 16.8 MB
    float*  cval = (float*) (ws + off); off += (size_t)B_ROWS * CCAP * 4;   // 16.8 MB
    int*    ccnt = (int*)   (ws + off); off += (size_t)B_ROWS * 4;          // 0.26 MB
    float*  vals = (float*) (ws + off); off += (size_t)B_ROWS * K_SEL * 4;  // 8.4 MB
    int*    idxs = (int*)   (ws + off);                                     // 8.4 MB

    hipLaunchKernelGGL(prep_kernel, dim3(PREP_X + PREP_W + PREP_T), dim3(256), 0, stream,
                       x, W_enc, W_dec, xB, WeB, WdTb);
    hipLaunchKernelGGL(enc_mfma, dim3(D_LAT / 128, B_ROWS / 128), dim3(256), 0, stream,
                       xB, WeB, b_enc, latB);
    hipLaunchKernelGGL(topk_cand, dim3(B_ROWS / 4), dim3(256), 0, stream,
                       latB, cidx, cval, ccnt);
    // latB (parked in the sparse region) fully consumed; zero the sparse output
    // via the hardware fill path (~6.8 TB/s) so dec_kernel only scatters.
    hipMemsetAsync(sparse, 0, (size_t)B_ROWS * D_LAT * sizeof(float), stream);
    hipLaunchKernelGGL(refine_sel, dim3(B_ROWS / 4), dim3(256), 0, stream,
                       x, W_enc, b_enc, cidx, cval, ccnt, vals, idxs);
    hipLaunchKernelGGL(dec_kernel, dim3(B_ROWS / 4), dim3(256), 0, stream,
                       vals, idxs, WdTb, b_dec, recon, sparse);
}

// Round 26
// 1080.942 us; speedup vs baseline: 1.0109x; 1.0109x over previous
//
#include <hip/hip_runtime.h>
#include <cstdint>

#define B_ROWS 65536
#define D_IN   640
#define D_LAT  2560
#define K_SEL  32
#define NCAND  48
#define CCAP   64      // candidate capacity per row
#define DELTA  0.04f   // ambiguity half-window: covers bf16 ulp (0.0156) + GEMM err
// np-exact K-panel boundaries (OpenBLAS SKYLAKEX Q=192): 192+192+128+128
#define P1 192
#define P2 384
#define P3 512
// merged prep kernel block ranges
#define PREP_X  ((size_t)B_ROWS * D_IN / 1024)            // 40960
#define PREP_W  ((size_t)D_LAT * D_IN / 1024)             // 1600
#define PREP_T  ((D_LAT / 32) * (D_IN / 32))              // 1600

typedef __attribute__((ext_vector_type(8))) short short8;
typedef __attribute__((ext_vector_type(4))) float f32x4;

static __device__ __forceinline__ ushort f2bf(float f) {
    uint32_t u = __float_as_uint(f);
    u += 0x7fffu + ((u >> 16) & 1u);   // round-to-nearest-even
    return (ushort)(u >> 16);
}
static __device__ __forceinline__ float b2f(ushort u) {
    return __uint_as_float((uint32_t)u << 16);
}

// ---------------- merged prep: cvt x -> xB, cvt W_enc -> WeB, W_dec^T -> WdTb ----
__global__ __launch_bounds__(256) void prep_kernel(const float* __restrict__ x,
                                                   const float* __restrict__ We,
                                                   const float* __restrict__ Wd,
                                                   ushort* __restrict__ xB,
                                                   ushort* __restrict__ WeB,
                                                   ushort* __restrict__ WdTb) {
    __shared__ float t[32][33];
    const size_t b = blockIdx.x;
    if (b < PREP_X + PREP_W) {
        const float* src = (b < PREP_X) ? x : We;
        ushort* dst      = (b < PREP_X) ? xB : WeB;
        const size_t bb  = (b < PREP_X) ? b : (b - PREP_X);
        const size_t i = (bb * 256 + threadIdx.x) * 4;
        float4 v = *(const float4*)(src + i);
        ushort4 o;
        o.x = f2bf(v.x); o.y = f2bf(v.y); o.z = f2bf(v.z); o.w = f2bf(v.w);
        *(ushort4*)(dst + i) = o;
    } else {
        const int tb = (int)(b - PREP_X - PREP_W);
        const int j0 = (tb % (D_LAT / 32)) * 32;
        const int i0 = (tb / (D_LAT / 32)) * 32;
        const int tx = threadIdx.x & 31, ty = threadIdx.x >> 5;
#pragma unroll
        for (int q = 0; q < 4; ++q)
            t[ty + 8 * q][tx] = Wd[(size_t)(i0 + ty + 8 * q) * D_LAT + j0 + tx];
        __syncthreads();
#pragma unroll
        for (int q = 0; q < 4; ++q)
            WdTb[(size_t)(j0 + ty + 8 * q) * D_IN + i0 + tx] = f2bf(t[tx][ty + 8 * q]);
    }
}

// ---------------- bf16 MFMA filter GEMM -> bf16 latents (BK=64) ------------------
__global__ __launch_bounds__(256, 3) void enc_mfma(const ushort* __restrict__ A,
                                                   const ushort* __restrict__ Wb,
                                                   const float* __restrict__ bias,
                                                   ushort* __restrict__ C) {
    __shared__ ushort Al[128][72];   // pad 64->72 (144B row): 2-way conflicts = free
    __shared__ ushort Bl[128][72];
    const int tid = threadIdx.x;
    const int n0 = blockIdx.x * 128;
    const int m0 = blockIdx.y * 128;
    const int srow = tid >> 1, shalf = tid & 1;   // 2 threads/row, 64B each
    const ushort* Ap = A  + (size_t)(m0 + srow) * D_IN + shalf * 32;
    const ushort* Bp = Wb + (size_t)(n0 + srow) * D_IN + shalf * 32;

    const int w = tid >> 6, l = tid & 63;
    const int wm = w >> 1, wn = w & 1;
    const int fr = l & 15, ko = l >> 4;

    f32x4 acc[4][4];
#pragma unroll
    for (int i = 0; i < 4; ++i)
#pragma unroll
        for (int j = 0; j < 4; ++j) acc[i][j] = (f32x4)0.0f;

    uint4 a0, a1, a2, a3, b0, b1, b2, b3;
#define LOADT(KT)                                                    \
    {                                                                \
        const uint* ap = (const uint*)(Ap + (KT) * 64);              \
        a0 = *(const uint4*)(ap);                                    \
        a1 = *(const uint4*)(ap + 4);                                \
        a2 = *(const uint4*)(ap + 8);                                \
        a3 = *(const uint4*)(ap + 12);                               \
        const uint* bp = (const uint*)(Bp + (KT) * 64);              \
        b0 = *(const uint4*)(bp);                                    \
        b1 = *(const uint4*)(bp + 4);                                \
        b2 = *(const uint4*)(bp + 8);                                \
        b3 = *(const uint4*)(bp + 12);                               \
    }

    LOADT(0);
    const int NT = D_IN / 64;   // 10
    for (int kt = 0; kt < NT; ++kt) {
        *(uint4*)&Al[srow][shalf * 32]      = a0;
        *(uint4*)&Al[srow][shalf * 32 + 8]  = a1;
        *(uint4*)&Al[srow][shalf * 32 + 16] = a2;
        *(uint4*)&Al[srow][shalf * 32 + 24] = a3;
        *(uint4*)&Bl[srow][shalf * 32]      = b0;
        *(uint4*)&Bl[srow][shalf * 32 + 8]  = b1;
        *(uint4*)&Bl[srow][shalf * 32 + 16] = b2;
        *(uint4*)&Bl[srow][shalf * 32 + 24] = b3;
        __syncthreads();
        if (kt + 1 < NT) LOADT(kt + 1);

#pragma unroll
        for (int ks = 0; ks < 2; ++ks) {
            short8 af[4], bf[4];
#pragma unroll
            for (int fm = 0; fm < 4; ++fm)
                af[fm] = *(const short8*)&Al[wm * 64 + fm * 16 + fr][ks * 32 + ko * 8];
#pragma unroll
            for (int fn = 0; fn < 4; ++fn)
                bf[fn] = *(const short8*)&Bl[wn * 64 + fn * 16 + fr][ks * 32 + ko * 8];
#pragma unroll
            for (int fm = 0; fm < 4; ++fm)
#pragma unroll
                for (int fn = 0; fn < 4; ++fn)
                    acc[fm][fn] = __builtin_amdgcn_mfma_f32_16x16x32_bf16(
                        af[fm], bf[fn], acc[fm][fn], 0, 0, 0);
        }
        __syncthreads();
    }
#undef LOADT

#pragma unroll
    for (int fn = 0; fn < 4; ++fn) {
        const int col = n0 + wn * 64 + fn * 16 + fr;
        const float bb = bias[col];
#pragma unroll
        for (int fm = 0; fm < 4; ++fm) {
#pragma unroll
            for (int j = 0; j < 4; ++j) {
                const int row = m0 + wm * 64 + fm * 16 + ko * 4 + j;
                C[(size_t)row * D_LAT + col] = f2bf(acc[fm][fn][j] + bb);
            }
        }
    }
}

// ---------------- Candidate select by threshold (wave-per-row, bf16 latents) -----
// If szero != null, also zeroes this block's 4 sparse rows (overlapped with
// compute; legal only when latB lives in workspace, not the sparse region).
__global__ __launch_bounds__(256) void topk_cand(const ushort* __restrict__ lat,
                                                 int* __restrict__ cidx,
                                                 float* __restrict__ cval,
                                                 int* __restrict__ ccnt,
                                                 float* __restrict__ szero) {
    const int wv = threadIdx.x >> 6, lane = threadIdx.x & 63;
    const int r = blockIdx.x * 4 + wv;
    const ushort* row = lat + (size_t)r * D_LAT;

    float v[5][8];
#pragma unroll
    for (int e = 0; e < 5; ++e) {
        const uint4 u = *(const uint4*)(row + e * 512 + lane * 8);
        v[e][0] = __uint_as_float(u.x << 16);
        v[e][1] = __uint_as_float(u.x & 0xffff0000u);
        v[e][2] = __uint_as_float(u.y << 16);
        v[e][3] = __uint_as_float(u.y & 0xffff0000u);
        v[e][4] = __uint_as_float(u.z << 16);
        v[e][5] = __uint_as_float(u.z & 0xffff0000u);
        v[e][6] = __uint_as_float(u.w << 16);
        v[e][7] = __uint_as_float(u.w & 0xffff0000u);
    }

    // overlapped sparse-zeroing: 4 rows * 640 float4 per block
    if (szero) {
        float4 z; z.x = z.y = z.z = z.w = 0.f;
        float4* s4 = (float4*)(szero + (size_t)blockIdx.x * 4 * D_LAT);
        for (int i = threadIdx.x; i < D_LAT; i += 256) s4[i] = z;
    }

    float mx = v[0][0];
#pragma unroll
    for (int e = 0; e < 5; ++e)
#pragma unroll
        for (int t = 0; t < 8; ++t) mx = fmaxf(mx, v[e][t]);
#pragma unroll
    for (int off = 1; off < 64; off <<= 1) mx = fmaxf(mx, __shfl_xor(mx, off));

    auto countGt = [&](float t) -> int {
        int c = 0;
#pragma unroll
        for (int e = 0; e < 5; ++e)
#pragma unroll
            for (int q = 0; q < 8; ++q) c += (v[e][q] > t);
#pragma unroll
        for (int off = 1; off < 64; off <<= 1) c += __shfl_xor(c, off);
        return c;
    };

    float lo = mx - 2.0f;
    int clo = countGt(lo);
    if (clo < NCAND) { lo = mx - 4.0f; clo = countGt(lo); }
    if (clo < NCAND) { lo = mx - 16.0f; clo = countGt(lo); }   // paranoia tier
    float hi = mx;
    for (int it = 0; it < 28 && clo > CCAP; ++it) {
        const float mid = 0.5f * (lo + hi);
        const int c = countGt(mid);
        if (c >= NCAND) { lo = mid; clo = c; } else hi = mid;
    }

    int base = 0;
#pragma unroll
    for (int e = 0; e < 5; ++e) {
#pragma unroll
        for (int q = 0; q < 8; ++q) {
            const float val = v[e][q];
            const bool take = val > lo;
            const uint64_t m = __ballot(take);
            const int pos = base + __popcll(m & ((1ull << lane) - 1ull));
            if (take && pos < CCAP) {
                cidx[(size_t)r * CCAP + pos] = e * 512 + lane * 8 + q;
                cval[(size_t)r * CCAP + pos] = val;
            }
            base += __popcll(m);
        }
    }
    if (lane == 0) ccnt[r] = (base < CCAP) ? base : CCAP;
}

// ---------------- Boundary-window refine + select (wave-per-row) -----------------
__global__ __launch_bounds__(256, 4) void refine_sel(const float* __restrict__ x,
                                                     const float* __restrict__ We,
                                                     const float* __restrict__ be,
                                                     const int* __restrict__ cidx,
                                                     const float* __restrict__ cval,
                                                     const int* __restrict__ ccnt,
                                                     float* __restrict__ vals,
                                                     int* __restrict__ idxs) {
    const int wv = threadIdx.x >> 6, lane = threadIdx.x & 63;
    const int r = blockIdx.x * 4 + wv;

    __shared__ float xs[4][656];     // panel bases 0,196,392,524 (banks 0,4,8,12)
    __shared__ int   winj[4][CCAP];
    __shared__ float exv[4][CCAP];

    const int cnt = ccnt[r];

    if (lane < K_SEL) {
        vals[(size_t)r * K_SEL + lane] = 0.f;
        idxs[(size_t)r * K_SEL + lane] = 0;
    }

    for (int i = lane; i < D_IN; i += 64) {
        const int p  = (i >= P3) ? 3 : (i >= P2) ? 2 : (i >= P1) ? 1 : 0;
        const int kb = (p == 0) ? 0 : (p == 1) ? P1  : (p == 2) ? P2  : P3;
        const int pb = (p == 0) ? 0 : (p == 1) ? 196 : (p == 2) ? 392 : 524;
        xs[wv][pb + i - kb] = x[(size_t)r * D_IN + i];
    }

    float v = -__builtin_inff(); int j = 0x7fffffff;
    if (lane < cnt) {
        j = cidx[(size_t)r * CCAP + lane];
        v = cval[(size_t)r * CCAP + lane];
    }

    float mxv = v, mnv = (lane < cnt) ? v : __builtin_inff();
#pragma unroll
    for (int off = 1; off < 64; off <<= 1) {
        mxv = fmaxf(mxv, __shfl_xor(mxv, off));
        mnv = fminf(mnv, __shfl_xor(mnv, off));
    }
    auto cgt = [&](float t) -> int {
        int c = (v > t) ? 1 : 0;
#pragma unroll
        for (int off = 1; off < 64; off <<= 1) c += __shfl_xor(c, off);
        return c;
    };
    float blo = mnv - 0.01f, bhi = mxv;
    for (int it = 0; it < 20; ++it) {
        const float mid = 0.5f * (blo + bhi);
        if (cgt(mid) >= K_SEL) blo = mid; else bhi = mid;
    }
    const float v32a = blo;
    const bool sure_in = (lane < cnt) && (v > v32a + DELTA);
    const bool inwin   = (lane < cnt) && !sure_in && (v > v32a - DELTA);
    const int n_in = __popcll(__ballot(sure_in));
    const uint64_t wm = __ballot(inwin);
    const int wcnt = __popcll(wm);
    if (inwin) winj[wv][__popcll(wm & ((1ull << lane) - 1ull))] = j;

    __syncthreads();

#define BURST(B)                                                     \
    {                                                                \
        const float4 w0 = wp4[(B) * 4 + 0], w1 = wp4[(B) * 4 + 1];   \
        const float4 w2 = wp4[(B) * 4 + 2], w3 = wp4[(B) * 4 + 3];   \
        const float4 x0 = xp4[(B) * 4 + 0], x1 = xp4[(B) * 4 + 1];   \
        const float4 x2 = xp4[(B) * 4 + 2], x3 = xp4[(B) * 4 + 3];   \
        a = fmaf(w0.x, x0.x, a); a = fmaf(w0.y, x0.y, a);            \
        a = fmaf(w0.z, x0.z, a); a = fmaf(w0.w, x0.w, a);            \
        a = fmaf(w1.x, x1.x, a); a = fmaf(w1.y, x1.y, a);            \
        a = fmaf(w1.z, x1.z, a); a = fmaf(w1.w, x1.w, a);            \
        a = fmaf(w2.x, x2.x, a); a = fmaf(w2.y, x2.y, a);            \
        a = fmaf(w2.z, x2.z, a); a = fmaf(w2.w, x2.w, a);            \
        a = fmaf(w3.x, x3.x, a); a = fmaf(w3.y, x3.y, a);            \
        a = fmaf(w3.z, x3.z, a); a = fmaf(w3.w, x3.w, a);            \
    }

    for (int p0 = 0; p0 < wcnt; p0 += 16) {
        const int rank = p0 + (lane >> 2), pnl = lane & 3;
        float a = 0.f; int jj = 0;
        if (rank < wcnt) {
            jj = winj[wv][rank];
            const int k0 = (pnl == 0) ? 0 : (pnl == 1) ? P1  : (pnl == 2) ? P2  : P3;
            const int pb = (pnl == 0) ? 0 : (pnl == 1) ? 196 : (pnl == 2) ? 392 : 524;
            const float4* wp4 = (const float4*)(We + (size_t)jj * D_IN + k0);
            const float4* xp4 = (const float4*)&xs[wv][pb];
            if (pnl < 2) {
#pragma unroll
                for (int b = 0; b < 12; ++b) BURST(b)
            } else {
#pragma unroll
                for (int b = 0; b < 8; ++b) BURST(b)
            }
        }
        const int gb = lane & ~3;
        const float a0 = __shfl(a, gb + 0), a1 = __shfl(a, gb + 1);
        const float a2 = __shfl(a, gb + 2), a3 = __shfl(a, gb + 3);
        if (pnl == 0 && rank < wcnt)
            exv[wv][rank] = (((a0 + a1) + a2) + a3) + be[jj];
    }
#undef BURST
    __syncthreads();

    const uint64_t sm = __ballot(sure_in);
    if (sure_in) {
        const int pos = __popcll(sm & ((1ull << lane) - 1ull));
        vals[(size_t)r * K_SEL + pos] = v;
        idxs[(size_t)r * K_SEL + pos] = j;
    }

    float ev = (lane < wcnt) ? exv[wv][lane] : -__builtin_inff();
    int   ej = (lane < wcnt) ? winj[wv][lane] : 0x7fffffff;
    int need = K_SEL - n_in;
    if (need > wcnt) need = wcnt;    // defensive
    for (int t = 0; t < need; ++t) {
        float bv = ev; int bi = ej;
#pragma unroll
        for (int off = 1; off < 64; off <<= 1) {
            float ov = __shfl_xor(bv, off);
            int   oi = __shfl_xor(bi, off);
            if (ov > bv || (ov == bv && oi < bi)) { bv = ov; bi = oi; }
        }
        if (ej == bi && ej != 0x7fffffff) {   // unique winner lane
            vals[(size_t)r * K_SEL + n_in + t] = ev;
            idxs[(size_t)r * K_SEL + n_in + t] = ej;
            ev = -__builtin_inff(); ej = 0x7fffffff;
        }
    }
}

// ---------------- Decoder + sparse scatter (zeros provided upstream) -------------
__global__ __launch_bounds__(256) void dec_kernel(const float* __restrict__ vals,
                                                  const int* __restrict__ idxs,
                                                  const ushort* __restrict__ WdTb,
                                                  const float* __restrict__ bdec,
                                                  float* __restrict__ recon,
                                                  float* __restrict__ sparse) {
    const int wave = threadIdx.x >> 6, lane = threadIdx.x & 63;
    const int r = blockIdx.x * 4 + wave;

    float lv = 0.f; int li = 0;
    if (lane < K_SEL) {
        lv = vals[(size_t)r * K_SEL + lane];
        li = idxs[(size_t)r * K_SEL + lane];
        li = (li < 0) ? 0 : ((li >= D_LAT) ? D_LAT - 1 : li);   // defensive clamp
    }
    // scatter early (sparse already zeroed upstream)
    if (lane < K_SEL && lv != 0.f) sparse[(size_t)r * D_LAT + li] = lv;

    float acc[10];
    {
        const float2* bd2 = (const float2*)bdec;
#pragma unroll
        for (int t = 0; t < 5; ++t) {
            const float2 b2 = bd2[lane * 5 + t];
            acc[2 * t] = b2.x; acc[2 * t + 1] = b2.y;
        }
    }

#pragma unroll 4
    for (int k = 0; k < K_SEL; ++k) {
        float vkv = __shfl(lv, k);
        int   jj  = __shfl(li, k);
        const uint* wu = (const uint*)(WdTb + (size_t)jj * D_IN);
#pragma unroll
        for (int t = 0; t < 5; ++t) {
            const uint u = wu[lane * 5 + t];
            acc[2 * t]     = fmaf(vkv, __uint_as_float(u << 16), acc[2 * t]);
            acc[2 * t + 1] = fmaf(vkv, __uint_as_float(u & 0xffff0000u), acc[2 * t + 1]);
        }
    }
    float2* out2 = (float2*)(recon + (size_t)r * D_IN);
#pragma unroll
    for (int t = 0; t < 5; ++t) {
        float2 o; o.x = acc[2 * t]; o.y = acc[2 * t + 1];
        out2[lane * 5 + t] = o;
    }
}

extern "C" void kernel_launch(void* const* d_in, const int* in_sizes, int n_in,
                              void* d_out, int out_size, void* d_ws, size_t ws_size,
                              hipStream_t stream) {
    const float* x     = (const float*)d_in[0];
    const float* W_enc = (const float*)d_in[1];
    const float* b_enc = (const float*)d_in[2];
    const float* W_dec = (const float*)d_in[3];
    const float* b_dec = (const float*)d_in[4];

    float* recon  = (float*)d_out;                                  // [B][640]
    float* sparse = (float*)d_out + (size_t)B_ROWS * D_IN;          // [B][2560]

    ushort* xB = (ushort*)recon;    // bf16 x parks in recon region (84 MB)

    char* ws = (char*)d_ws;
    size_t off = 0;
    ushort* WdTb = (ushort*)(ws + off); off += (size_t)D_LAT * D_IN * 2;    // 3.28 MB
    ushort* WeB  = (ushort*)(ws + off); off += (size_t)D_LAT * D_IN * 2;    // 3.28 MB
    int*    cidx = (int*)   (ws + off); off += (size_t)B_ROWS * CCAP * 4;   // 16.8 MB
    float*  cval = (float*) (ws + off); off += (size_t)B_ROWS * CCAP * 4;   // 16.8 MB
    int*    ccnt = (int*)   (ws + off); off += (size_t)B_ROWS * 4;          // 0.26 MB
    float*  vals = (float*) (ws + off); off += (size_t)B_ROWS * K_SEL * 4;  // 8.4 MB
    int*    idxs = (int*)   (ws + off); off += (size_t)B_ROWS * K_SEL * 4;  // 8.4 MB

    // latB: prefer workspace (enables overlapped sparse-zeroing in topk_cand);
    // fall back to parking in the sparse region + memset (R25 passing path).
    const size_t latB_bytes = (size_t)B_ROWS * D_LAT * 2;                   // 336 MB
    const bool big_ws = (ws_size >= off + latB_bytes);
    ushort* latB = big_ws ? (ushort*)(ws + off) : (ushort*)sparse;

    hipLaunchKernelGGL(prep_kernel, dim3(PREP_X + PREP_W + PREP_T), dim3(256), 0, stream,
                       x, W_enc, W_dec, xB, WeB, WdTb);
    hipLaunchKernelGGL(enc_mfma, dim3(D_LAT / 128, B_ROWS / 128), dim3(256), 0, stream,
                       xB, WeB, b_enc, latB);
    if (big_ws) {
        hipLaunchKernelGGL(topk_cand, dim3(B_ROWS / 4), dim3(256), 0, stream,
                           latB, cidx, cval, ccnt, sparse);
    } else {
        hipLaunchKernelGGL(topk_cand, dim3(B_ROWS / 4), dim3(256), 0, stream,
                           latB, cidx, cval, ccnt, (float*)nullptr);
        hipMemsetAsync(sparse, 0, (size_t)B_ROWS * D_LAT * sizeof(float), stream);
    }
    hipLaunchKernelGGL(refine_sel, dim3(B_ROWS / 4), dim3(256), 0, stream,
                       x, W_enc, b_enc, cidx, cval, ccnt, vals, idxs);
    hipLaunchKernelGGL(dec_kernel, dim3(B_ROWS / 4), dim3(256), 0, stream,
                       vals, idxs, WdTb, b_dec, recon, sparse);
}